// Round 1
// baseline (1840.419 us; speedup 1.0000x reference)
//
#include <hip/hip_runtime.h>
#include <hip/hip_bf16.h>
#include <math.h>

#define N_NODES 100000
#define N_EDGES 3200000
#define NB 16           // nodes per block-iteration
#define EPSV 1e-8f

// ---------------- edge scatter: acc[n][0..8] += frames[e], acc[n][9] += 1 ----
__global__ void edge_kernel(const float* __restrict__ frames,
                            const int* __restrict__ row,
                            float* __restrict__ acc) {
  int e = blockIdx.x * blockDim.x + threadIdx.x;
  if (e >= N_EDGES) return;
  int n = row[e];
  const float* f = frames + (size_t)e * 9;
  float* a = acc + (size_t)n * 10;
#pragma unroll
  for (int k = 0; k < 9; ++k) unsafeAtomicAdd(a + k, f[k]);
  unsafeAtomicAdd(a + 9, 1.0f);
}

// ---------------- node phase: everything else -------------------------------
__global__ __launch_bounds__(256, 2) void node_kernel(
    const float* __restrict__ scalar_rep,   // [N][128]
    const float* __restrict__ vrep,         // [N][16][3]
    const float* __restrict__ Wd,           // [16][16]  (HID, V_IN)
    const float* __restrict__ Wf,           // [3][16]
    const float* __restrict__ Ws,           // [128][153]
    const float* __restrict__ bs,           // [128]
    const float* __restrict__ Wu,           // [16][16]  (V_OUT, HID)
    const float* __restrict__ Wg,           // [16][128]
    const float* __restrict__ bg,           // [16]
    const float* __restrict__ acc,          // [N][10] edge sums + count
    float* __restrict__ out_s,              // [N][128]
    float* __restrict__ out_v) {            // [N][16][3]
  __shared__ __hip_bfloat16 s_Ws[128 * 154];   // stride 154 -> odd dword stride
  __shared__ float s_merged[NB][160];          // [0:128] scalar, [128:144] vnorm, [144:153] SH
  __shared__ float s_vrep[NB][48];
  __shared__ float s_vh[NB][48];               // [i][t*16+h]
  __shared__ float s_vdf[NB][12];              // [i][t*3+f]
  __shared__ float s_sf[NB][128];              // silu(s_out)
  __shared__ float s_gate[NB][16];             // sigmoid(gate)
  __shared__ float s_WdT[256];                 // [v][h]
  __shared__ float s_WuT[256];                 // [h][vo]
  __shared__ float s_WgT[2048];                // [s][v]
  __shared__ float s_Wf[48];
  __shared__ float s_bs[128];
  __shared__ float s_bg[16];

  const int tid = threadIdx.x;

  // preload weights (once per block)
  for (int idx = tid; idx < 128 * 153; idx += 256) {
    int o = idx / 153, m = idx - o * 153;
    s_Ws[o * 154 + m] = __float2bfloat16(Ws[idx]);
  }
  {
    int a = tid >> 4, b = tid & 15;
    s_WdT[b * 16 + a] = Wd[tid];   // Wd[h=a][v=b] -> [v][h]
    s_WuT[b * 16 + a] = Wu[tid];   // Wu[vo=a][h=b] -> [h][vo]
  }
  for (int idx = tid; idx < 2048; idx += 256) {
    int v = idx >> 7, s = idx & 127;
    s_WgT[s * 16 + v] = Wg[idx];   // [v][s] -> [s][v]
  }
  if (tid < 48) s_Wf[tid] = Wf[tid];
  if (tid < 128) s_bs[tid] = bs[tid];
  if (tid < 16) s_bg[tid] = bg[tid];

  const int i4 = tid >> 4;     // node within group for 16-wide phases
  const int j4 = tid & 15;

  for (int g = blockIdx.x; g < N_NODES / NB; g += gridDim.x) {
    const int n0 = g * NB;
    __syncthreads();  // previous iteration fully done; weights visible
    // stage vector_rep + scalar part of merged (coalesced)
    for (int idx = tid; idx < NB * 48; idx += 256)
      ((float*)s_vrep)[idx] = vrep[(size_t)n0 * 48 + idx];
    for (int idx = tid; idx < NB * 128; idx += 256) {
      int i = idx >> 7, m = idx & 127;
      s_merged[i][m] = scalar_rep[(size_t)n0 * 128 + idx];
    }
    __syncthreads();
    // vh + vnorm: thread (i4 = node, j4 = h)
    {
      float a0 = 0.f, a1 = 0.f, a2 = 0.f;
#pragma unroll
      for (int v = 0; v < 16; ++v) {
        float w = s_WdT[v * 16 + j4];
        a0 += s_vrep[i4][v * 3 + 0] * w;
        a1 += s_vrep[i4][v * 3 + 1] * w;
        a2 += s_vrep[i4][v * 3 + 2] * w;
      }
      s_vh[i4][j4]      = a0;
      s_vh[i4][16 + j4] = a1;
      s_vh[i4][32 + j4] = a2;
      s_merged[i4][128 + j4] = sqrtf(a0 * a0 + a1 * a1 + a2 * a2 + EPSV);
    }
    // vdf: thread (i4, j4 = t*3+f), 9 active
    if (j4 < 9) {
      int t = j4 / 3, f = j4 - t * 3;
      float a = 0.f;
#pragma unroll
      for (int v = 0; v < 16; ++v)
        a += s_vrep[i4][v * 3 + t] * s_Wf[f * 16 + v];
      s_vdf[i4][j4] = a;
    }
    __syncthreads();
    // scalar_hidden: SH[f*3+s] = sum_t Fsum[s*3+t]*vdf[t*3+f] / max(cnt,1)
    if (j4 < 9) {
      int f = j4 / 3, s = j4 - f * 3;
      const float* a = acc + (size_t)(n0 + i4) * 10;
      float c = fmaxf(a[9], 1.0f);
      float sum = a[s * 3 + 0] * s_vdf[i4][0 + f] +
                  a[s * 3 + 1] * s_vdf[i4][3 + f] +
                  a[s * 3 + 2] * s_vdf[i4][6 + f];
      s_merged[i4][144 + j4] = sum / c;
    }
    __syncthreads();
    // big matvec: s_out[o] = bs[o] + sum_m Ws[o][m]*merged[m]; thread = (o, half)
    {
      const int o = tid & 127, half = tid >> 7;
      float accs[8];
      float b = s_bs[o];
#pragma unroll
      for (int i = 0; i < 8; ++i) accs[i] = b;
      const __hip_bfloat16* wr = s_Ws + o * 154;
      for (int m = 0; m < 153; ++m) {
        float w = __bfloat162float(wr[m]);
#pragma unroll
        for (int i = 0; i < 8; ++i) accs[i] += w * s_merged[half * 8 + i][m];
      }
#pragma unroll
      for (int i = 0; i < 8; ++i) {
        float x = accs[i];
        float sf = x / (1.0f + __expf(-x));   // silu
        s_sf[half * 8 + i][o] = sf;
        out_s[(size_t)(n0 + half * 8 + i) * 128 + o] = sf;
      }
    }
    __syncthreads();
    // gate: thread (i4, j4 = v)
    {
      float a = s_bg[j4];
      for (int s = 0; s < 128; ++s) a += s_sf[i4][s] * s_WgT[s * 16 + j4];
      s_gate[i4][j4] = 1.0f / (1.0f + __expf(-a));
    }
    __syncthreads();
    // v_up + gated output: thread (i4, j4 = vout)
    {
      float b0 = 0.f, b1 = 0.f, b2 = 0.f;
#pragma unroll
      for (int h = 0; h < 16; ++h) {
        float w = s_WuT[h * 16 + j4];
        b0 += s_vh[i4][h]      * w;
        b1 += s_vh[i4][16 + h] * w;
        b2 += s_vh[i4][32 + h] * w;
      }
      float gt = s_gate[i4][j4];
      size_t base = (size_t)(n0 + i4) * 48 + (size_t)j4 * 3;
      out_v[base + 0] = b0 * gt;
      out_v[base + 1] = b1 * gt;
      out_v[base + 2] = b2 * gt;
    }
  }
}

extern "C" void kernel_launch(void* const* d_in, const int* in_sizes, int n_in,
                              void* d_out, int out_size, void* d_ws, size_t ws_size,
                              hipStream_t stream) {
  const float* scalar_rep = (const float*)d_in[0];
  const float* vector_rep = (const float*)d_in[1];
  const float* frames     = (const float*)d_in[2];
  const float* W_down     = (const float*)d_in[3];
  const float* W_frames   = (const float*)d_in[4];
  const float* W_scalar   = (const float*)d_in[5];
  const float* b_scalar   = (const float*)d_in[6];
  const float* W_up       = (const float*)d_in[7];
  const float* W_gate     = (const float*)d_in[8];
  const float* b_gate     = (const float*)d_in[9];
  const int*   edge_index = (const int*)d_in[10];   // [2][E], row = first E

  float* out = (float*)d_out;
  float* acc = (float*)d_ws;                        // [N][10]

  hipMemsetAsync(acc, 0, (size_t)N_NODES * 10 * sizeof(float), stream);
  edge_kernel<<<(N_EDGES + 255) / 256, 256, 0, stream>>>(frames, edge_index, acc);
  node_kernel<<<2048, 256, 0, stream>>>(
      scalar_rep, vector_rep, W_down, W_frames, W_scalar, b_scalar,
      W_up, W_gate, b_gate, acc,
      out, out + (size_t)N_NODES * 128);
}

// Round 2
// 492.033 us; speedup vs baseline: 3.7404x; 3.7404x over previous
//
#include <hip/hip_runtime.h>
#include <hip/hip_bf16.h>
#include <math.h>

#define N_NODES 100000
#define N_EDGES 3200000
#define NB 16           // nodes per block-iteration (node phase)
#define EPSV 1e-8f

#define NBUCK 1563                 // ceil(100000 / 64) buckets of 64 nodes
#define NCHUNK 512                 // edge chunks
#define CHUNK_E (N_EDGES / NCHUNK) // 6250 edges per chunk

// ---------------- A: per-chunk histogram of row>>6 (LDS atomics only) -------
__global__ __launch_bounds__(256) void hist_kernel(const int* __restrict__ row,
                                                   int* __restrict__ hist) {
  __shared__ int lh[NBUCK];
  for (int i = threadIdx.x; i < NBUCK; i += 256) lh[i] = 0;
  __syncthreads();
  const int c = blockIdx.x;
  const int e1 = c * CHUNK_E + CHUNK_E;
  for (int e = c * CHUNK_E + threadIdx.x; e < e1; e += 256)
    atomicAdd(&lh[row[e] >> 6], 1);
  __syncthreads();
  for (int i = threadIdx.x; i < NBUCK; i += 256)
    hist[(size_t)c * NBUCK + i] = lh[i];
}

// ---------------- B1: exclusive scan over chunks, per bucket ----------------
__global__ __launch_bounds__(256) void scanc_kernel(int* __restrict__ hist,
                                                    int* __restrict__ total) {
  __shared__ int s[2][NCHUNK];
  const int b = blockIdx.x;
  const int t = threadIdx.x;
  s[0][t]       = hist[(size_t)t * NBUCK + b];
  s[0][t + 256] = hist[(size_t)(t + 256) * NBUCK + b];
  __syncthreads();
  int src = 0;
  for (int off = 1; off < NCHUNK; off <<= 1) {
    int dst = src ^ 1;
    for (int i = t; i < NCHUNK; i += 256)
      s[dst][i] = s[src][i] + ((i >= off) ? s[src][i - off] : 0);
    __syncthreads();
    src = dst;
  }
  hist[(size_t)t * NBUCK + b]         = (t == 0) ? 0 : s[src][t - 1];
  hist[(size_t)(t + 256) * NBUCK + b] = s[src][t + 255];
  if (t == 0) total[b] = s[src][NCHUNK - 1];
}

// ---------------- B2: exclusive scan over buckets ---------------------------
__global__ __launch_bounds__(256) void scanb_kernel(const int* __restrict__ total,
                                                    int* __restrict__ base) {
  __shared__ int s[2][2048];
  const int t = threadIdx.x;
  for (int i = t; i < 2048; i += 256) s[0][i] = (i < NBUCK) ? total[i] : 0;
  __syncthreads();
  int src = 0;
  for (int off = 1; off < 2048; off <<= 1) {
    int dst = src ^ 1;
    for (int i = t; i < 2048; i += 256)
      s[dst][i] = s[src][i] + ((i >= off) ? s[src][i - off] : 0);
    __syncthreads();
    src = dst;
  }
  for (int i = t; i <= NBUCK; i += 256) base[i] = (i == 0) ? 0 : s[src][i - 1];
}

// ---------------- C: scatter packed edge ids into bucket order --------------
__global__ __launch_bounds__(256) void scatter_kernel(const int* __restrict__ row,
                                                      const int* __restrict__ hist,
                                                      const int* __restrict__ base,
                                                      int* __restrict__ sorted) {
  __shared__ int off[NBUCK];
  const int c = blockIdx.x;
  for (int i = threadIdx.x; i < NBUCK; i += 256)
    off[i] = hist[(size_t)c * NBUCK + i] + base[i];
  __syncthreads();
  const int e1 = c * CHUNK_E + CHUNK_E;
  for (int e = c * CHUNK_E + threadIdx.x; e < e1; e += 256) {
    int r = row[e];
    int p = atomicAdd(&off[r >> 6], 1);
    sorted[p] = (e << 6) | (r & 63);
  }
}

// ---------------- D: per-bucket reduce of frames into acc (LDS atomics) -----
__global__ __launch_bounds__(256) void reduce_kernel(const int* __restrict__ sorted,
                                                     const int* __restrict__ base,
                                                     const float* __restrict__ frames,
                                                     float* __restrict__ acc) {
  __shared__ float a[64 * 11];   // stride 11 -> odd bank stride
  const int b = blockIdx.x;
  for (int i = threadIdx.x; i < 64 * 11; i += 256) a[i] = 0.f;
  __syncthreads();
  const int p1 = base[b + 1];
  for (int p = base[b] + threadIdx.x; p < p1; p += 256) {
    int pk = sorted[p];
    int e = pk >> 6, node = pk & 63;
    const float* f = frames + (size_t)e * 9;
    float* an = a + node * 11;
#pragma unroll
    for (int k = 0; k < 9; ++k) atomicAdd(an + k, f[k]);
    atomicAdd(an + 9, 1.0f);
  }
  __syncthreads();
  const int n0 = b << 6;
  for (int i = threadIdx.x; i < 64 * 10; i += 256) {
    int node = i / 10, k = i - node * 10;
    int n = n0 + node;
    if (n < N_NODES) acc[(size_t)n * 10 + k] = a[node * 11 + k];
  }
}

// ---------------- node phase: everything else (unchanged) -------------------
__global__ __launch_bounds__(256, 2) void node_kernel(
    const float* __restrict__ scalar_rep,   // [N][128]
    const float* __restrict__ vrep,         // [N][16][3]
    const float* __restrict__ Wd,           // [16][16]  (HID, V_IN)
    const float* __restrict__ Wf,           // [3][16]
    const float* __restrict__ Ws,           // [128][153]
    const float* __restrict__ bs,           // [128]
    const float* __restrict__ Wu,           // [16][16]  (V_OUT, HID)
    const float* __restrict__ Wg,           // [16][128]
    const float* __restrict__ bg,           // [16]
    const float* __restrict__ acc,          // [N][10] edge sums + count
    float* __restrict__ out_s,              // [N][128]
    float* __restrict__ out_v) {            // [N][16][3]
  __shared__ __hip_bfloat16 s_Ws[128 * 154];   // stride 154 -> odd dword stride
  __shared__ float s_merged[NB][160];          // [0:128] scalar, [128:144] vnorm, [144:153] SH
  __shared__ float s_vrep[NB][48];
  __shared__ float s_vh[NB][48];               // [i][t*16+h]
  __shared__ float s_vdf[NB][12];              // [i][t*3+f]
  __shared__ float s_sf[NB][128];              // silu(s_out)
  __shared__ float s_gate[NB][16];             // sigmoid(gate)
  __shared__ float s_WdT[256];                 // [v][h]
  __shared__ float s_WuT[256];                 // [h][vo]
  __shared__ float s_WgT[2048];                // [s][v]
  __shared__ float s_Wf[48];
  __shared__ float s_bs[128];
  __shared__ float s_bg[16];

  const int tid = threadIdx.x;

  for (int idx = tid; idx < 128 * 153; idx += 256) {
    int o = idx / 153, m = idx - o * 153;
    s_Ws[o * 154 + m] = __float2bfloat16(Ws[idx]);
  }
  {
    int a = tid >> 4, b = tid & 15;
    s_WdT[b * 16 + a] = Wd[tid];
    s_WuT[b * 16 + a] = Wu[tid];
  }
  for (int idx = tid; idx < 2048; idx += 256) {
    int v = idx >> 7, s = idx & 127;
    s_WgT[s * 16 + v] = Wg[idx];
  }
  if (tid < 48) s_Wf[tid] = Wf[tid];
  if (tid < 128) s_bs[tid] = bs[tid];
  if (tid < 16) s_bg[tid] = bg[tid];

  const int i4 = tid >> 4;
  const int j4 = tid & 15;

  for (int g = blockIdx.x; g < N_NODES / NB; g += gridDim.x) {
    const int n0 = g * NB;
    __syncthreads();
    for (int idx = tid; idx < NB * 48; idx += 256)
      ((float*)s_vrep)[idx] = vrep[(size_t)n0 * 48 + idx];
    for (int idx = tid; idx < NB * 128; idx += 256) {
      int i = idx >> 7, m = idx & 127;
      s_merged[i][m] = scalar_rep[(size_t)n0 * 128 + idx];
    }
    __syncthreads();
    {
      float a0 = 0.f, a1 = 0.f, a2 = 0.f;
#pragma unroll
      for (int v = 0; v < 16; ++v) {
        float w = s_WdT[v * 16 + j4];
        a0 += s_vrep[i4][v * 3 + 0] * w;
        a1 += s_vrep[i4][v * 3 + 1] * w;
        a2 += s_vrep[i4][v * 3 + 2] * w;
      }
      s_vh[i4][j4]      = a0;
      s_vh[i4][16 + j4] = a1;
      s_vh[i4][32 + j4] = a2;
      s_merged[i4][128 + j4] = sqrtf(a0 * a0 + a1 * a1 + a2 * a2 + EPSV);
    }
    if (j4 < 9) {
      int t = j4 / 3, f = j4 - t * 3;
      float a = 0.f;
#pragma unroll
      for (int v = 0; v < 16; ++v)
        a += s_vrep[i4][v * 3 + t] * s_Wf[f * 16 + v];
      s_vdf[i4][j4] = a;
    }
    __syncthreads();
    if (j4 < 9) {
      int f = j4 / 3, s = j4 - f * 3;
      const float* a = acc + (size_t)(n0 + i4) * 10;
      float c = fmaxf(a[9], 1.0f);
      float sum = a[s * 3 + 0] * s_vdf[i4][0 + f] +
                  a[s * 3 + 1] * s_vdf[i4][3 + f] +
                  a[s * 3 + 2] * s_vdf[i4][6 + f];
      s_merged[i4][144 + j4] = sum / c;
    }
    __syncthreads();
    {
      const int o = tid & 127, half = tid >> 7;
      float accs[8];
      float bsv = s_bs[o];
#pragma unroll
      for (int i = 0; i < 8; ++i) accs[i] = bsv;
      const __hip_bfloat16* wr = s_Ws + o * 154;
      for (int m = 0; m < 153; ++m) {
        float w = __bfloat162float(wr[m]);
#pragma unroll
        for (int i = 0; i < 8; ++i) accs[i] += w * s_merged[half * 8 + i][m];
      }
#pragma unroll
      for (int i = 0; i < 8; ++i) {
        float x = accs[i];
        float sf = x / (1.0f + __expf(-x));
        s_sf[half * 8 + i][o] = sf;
        out_s[(size_t)(n0 + half * 8 + i) * 128 + o] = sf;
      }
    }
    __syncthreads();
    {
      float a = s_bg[j4];
      for (int s = 0; s < 128; ++s) a += s_sf[i4][s] * s_WgT[s * 16 + j4];
      s_gate[i4][j4] = 1.0f / (1.0f + __expf(-a));
    }
    __syncthreads();
    {
      float b0 = 0.f, b1 = 0.f, b2 = 0.f;
#pragma unroll
      for (int h = 0; h < 16; ++h) {
        float w = s_WuT[h * 16 + j4];
        b0 += s_vh[i4][h]      * w;
        b1 += s_vh[i4][16 + h] * w;
        b2 += s_vh[i4][32 + h] * w;
      }
      float gt = s_gate[i4][j4];
      size_t basep = (size_t)(n0 + i4) * 48 + (size_t)j4 * 3;
      out_v[basep + 0] = b0 * gt;
      out_v[basep + 1] = b1 * gt;
      out_v[basep + 2] = b2 * gt;
    }
  }
}

extern "C" void kernel_launch(void* const* d_in, const int* in_sizes, int n_in,
                              void* d_out, int out_size, void* d_ws, size_t ws_size,
                              hipStream_t stream) {
  const float* scalar_rep = (const float*)d_in[0];
  const float* vector_rep = (const float*)d_in[1];
  const float* frames     = (const float*)d_in[2];
  const float* W_down     = (const float*)d_in[3];
  const float* W_frames   = (const float*)d_in[4];
  const float* W_scalar   = (const float*)d_in[5];
  const float* b_scalar   = (const float*)d_in[6];
  const float* W_up       = (const float*)d_in[7];
  const float* W_gate     = (const float*)d_in[8];
  const float* b_gate     = (const float*)d_in[9];
  const int*   edge_index = (const int*)d_in[10];   // [2][E], row = first E

  float* out = (float*)d_out;

  // workspace layout (all 16B aligned)
  char* ws = (char*)d_ws;
  int*   hist   = (int*)ws;                                   // NCHUNK*NBUCK
  int*   total  = (int*)(ws + ((size_t)NCHUNK * NBUCK * 4 + 255) / 256 * 256);
  int*   base   = total + ((NBUCK + 63) / 64) * 64;           // NBUCK+1
  int*   sorted = base + ((NBUCK + 1 + 63) / 64) * 64;        // N_EDGES
  float* acc    = (float*)(sorted + N_EDGES);                 // N_NODES*10

  hist_kernel   <<<NCHUNK, 256, 0, stream>>>(edge_index, hist);
  scanc_kernel  <<<NBUCK,  256, 0, stream>>>(hist, total);
  scanb_kernel  <<<1,      256, 0, stream>>>(total, base);
  scatter_kernel<<<NCHUNK, 256, 0, stream>>>(edge_index, hist, base, sorted);
  reduce_kernel <<<NBUCK,  256, 0, stream>>>(sorted, base, frames, acc);

  node_kernel<<<2048, 256, 0, stream>>>(
      scalar_rep, vector_rep, W_down, W_frames, W_scalar, b_scalar,
      W_up, W_gate, b_gate, acc,
      out, out + (size_t)N_NODES * 128);
}

// Round 3
// 313.341 us; speedup vs baseline: 5.8735x; 1.5703x over previous
//
#include <hip/hip_runtime.h>
#include <hip/hip_bf16.h>
#include <math.h>

#define N_NODES 100000
#define N_EDGES 3200000
#define NB 16           // nodes per block-iteration (node phase)
#define EPSV 1e-8f

#define NBUCK 1563                 // ceil(100000 / 64) buckets of 64 nodes
#define NCHUNK 512                 // edge chunks
#define CHUNK_E (N_EDGES / NCHUNK) // 6250 edges per chunk

typedef __attribute__((ext_vector_type(8))) short short8;
typedef __attribute__((ext_vector_type(4))) float f32x4;

static __device__ __forceinline__ unsigned short f2bf(float x) {
  union { float f; unsigned int u; } c; c.f = x;
  unsigned int r = c.u + 0x7fff + ((c.u >> 16) & 1);   // RNE
  return (unsigned short)(r >> 16);
}

// ---------------- A: per-chunk histogram of row>>6 (LDS atomics only) -------
__global__ __launch_bounds__(256) void hist_kernel(const int* __restrict__ row,
                                                   int* __restrict__ hist) {
  __shared__ int lh[NBUCK];
  for (int i = threadIdx.x; i < NBUCK; i += 256) lh[i] = 0;
  __syncthreads();
  const int c = blockIdx.x;
  const int e1 = c * CHUNK_E + CHUNK_E;
  for (int e = c * CHUNK_E + threadIdx.x; e < e1; e += 256)
    atomicAdd(&lh[row[e] >> 6], 1);
  __syncthreads();
  for (int i = threadIdx.x; i < NBUCK; i += 256)
    hist[(size_t)c * NBUCK + i] = lh[i];
}

// ---------------- B1: exclusive scan over chunks, per bucket ----------------
__global__ __launch_bounds__(256) void scanc_kernel(int* __restrict__ hist,
                                                    int* __restrict__ total) {
  __shared__ int s[2][NCHUNK];
  const int b = blockIdx.x;
  const int t = threadIdx.x;
  s[0][t]       = hist[(size_t)t * NBUCK + b];
  s[0][t + 256] = hist[(size_t)(t + 256) * NBUCK + b];
  __syncthreads();
  int src = 0;
  for (int off = 1; off < NCHUNK; off <<= 1) {
    int dst = src ^ 1;
    for (int i = t; i < NCHUNK; i += 256)
      s[dst][i] = s[src][i] + ((i >= off) ? s[src][i - off] : 0);
    __syncthreads();
    src = dst;
  }
  hist[(size_t)t * NBUCK + b]         = (t == 0) ? 0 : s[src][t - 1];
  hist[(size_t)(t + 256) * NBUCK + b] = s[src][t + 255];
  if (t == 0) total[b] = s[src][NCHUNK - 1];
}

// ---------------- B2: exclusive scan over buckets ---------------------------
__global__ __launch_bounds__(256) void scanb_kernel(const int* __restrict__ total,
                                                    int* __restrict__ base) {
  __shared__ int s[2][2048];
  const int t = threadIdx.x;
  for (int i = t; i < 2048; i += 256) s[0][i] = (i < NBUCK) ? total[i] : 0;
  __syncthreads();
  int src = 0;
  for (int off = 1; off < 2048; off <<= 1) {
    int dst = src ^ 1;
    for (int i = t; i < 2048; i += 256)
      s[dst][i] = s[src][i] + ((i >= off) ? s[src][i - off] : 0);
    __syncthreads();
    src = dst;
  }
  for (int i = t; i <= NBUCK; i += 256) base[i] = (i == 0) ? 0 : s[src][i - 1];
}

// ---------------- C: scatter packed edge ids into bucket order --------------
__global__ __launch_bounds__(256) void scatter_kernel(const int* __restrict__ row,
                                                      const int* __restrict__ hist,
                                                      const int* __restrict__ base,
                                                      int* __restrict__ sorted) {
  __shared__ int off[NBUCK];
  const int c = blockIdx.x;
  for (int i = threadIdx.x; i < NBUCK; i += 256)
    off[i] = hist[(size_t)c * NBUCK + i] + base[i];
  __syncthreads();
  const int e1 = c * CHUNK_E + CHUNK_E;
  for (int e = c * CHUNK_E + threadIdx.x; e < e1; e += 256) {
    int r = row[e];
    int p = atomicAdd(&off[r >> 6], 1);
    sorted[p] = (e << 6) | (r & 63);
  }
}

// ---------------- D: per-bucket reduce of frames into acc (LDS atomics) -----
__global__ __launch_bounds__(256) void reduce_kernel(const int* __restrict__ sorted,
                                                     const int* __restrict__ base,
                                                     const float* __restrict__ frames,
                                                     float* __restrict__ acc) {
  __shared__ float a[64 * 11];   // stride 11 -> odd bank stride
  const int b = blockIdx.x;
  for (int i = threadIdx.x; i < 64 * 11; i += 256) a[i] = 0.f;
  __syncthreads();
  const int p1 = base[b + 1];
  for (int p = base[b] + threadIdx.x; p < p1; p += 256) {
    int pk = sorted[p];
    int e = pk >> 6, node = pk & 63;
    const float* f = frames + (size_t)e * 9;
    float* an = a + node * 11;
#pragma unroll
    for (int k = 0; k < 9; ++k) atomicAdd(an + k, f[k]);
    atomicAdd(an + 9, 1.0f);
  }
  __syncthreads();
  const int n0 = b << 6;
  for (int i = threadIdx.x; i < 64 * 10; i += 256) {
    int node = i / 10, k = i - node * 10;
    int n = n0 + node;
    if (n < N_NODES) acc[(size_t)n * 10 + k] = a[node * 11 + k];
  }
}

// ---------------- prep: pre-swizzle Ws/Wg into MFMA B-fragment layout -------
__global__ __launch_bounds__(256) void prep_kernel(const float* __restrict__ Ws,
                                                   const float* __restrict__ Wg,
                                                   unsigned short* __restrict__ wsWs,
                                                   unsigned short* __restrict__ wsWg) {
  int idx = blockIdx.x * 256 + threadIdx.x;     // 80 blocks -> 20480 threads
  if (idx < 8 * 5 * 512) {                      // ((nt*5+kk)*64 + l)*8 + j
    int j = idx & 7, l = (idx >> 3) & 63, t = idx >> 9;
    int nt = t / 5, kk = t - nt * 5;
    int o = nt * 16 + (l & 15);
    int m = kk * 32 + ((l >> 4) << 3) + j;
    wsWs[idx] = (m < 153) ? f2bf(Ws[o * 153 + m]) : (unsigned short)0;
  }
  if (idx < 4 * 512) {                          // ((kk*64 + l)*8 + j)
    int j = idx & 7, l = (idx >> 3) & 63, kk = idx >> 9;
    int v = l & 15;
    int m = kk * 32 + ((l >> 4) << 3) + j;
    wsWg[idx] = f2bf(Wg[v * 128 + m]);
  }
}

// ---------------- node phase: MFMA for big matvec + gate --------------------
__global__ __launch_bounds__(256, 4) void node_kernel(
    const float* __restrict__ scalar_rep,   // [N][128]
    const float* __restrict__ vrep,         // [N][16][3]
    const float* __restrict__ Wd,           // [16][16]
    const float* __restrict__ Wf,           // [3][16]
    const float* __restrict__ bs,           // [128]
    const float* __restrict__ Wu,           // [16][16]
    const float* __restrict__ bg,           // [16]
    const unsigned short* __restrict__ wsWs,// pre-swizzled B-frags [8][5][64][8]
    const unsigned short* __restrict__ wsWg,// pre-swizzled B-frags [4][64][8]
    const float* __restrict__ acc,          // [N][10]
    float* __restrict__ out_s,              // [N][128]
    float* __restrict__ out_v) {            // [N][16][3]
  __shared__ alignas(16) unsigned short s_mergedb[16 * 168];  // bf16, pad->168
  __shared__ alignas(16) unsigned short s_sfb[16 * 136];      // bf16 silu
  __shared__ float s_vrep[16][48];
  __shared__ float s_vh[16][48];
  __shared__ float s_vdf[16][12];
  __shared__ float s_gate[16][16];
  __shared__ float s_WdT[256], s_WuT[256], s_Wf[48], s_bs[128], s_bg[16];

  const int tid = threadIdx.x;
  {
    int a = tid >> 4, b = tid & 15;
    s_WdT[b * 16 + a] = Wd[tid];
    s_WuT[b * 16 + a] = Wu[tid];
  }
  if (tid < 48) s_Wf[tid] = Wf[tid];
  if (tid < 128) s_bs[tid] = bs[tid];
  if (tid < 16) s_bg[tid] = bg[tid];
  if (tid < 240) {                       // zero merged pad cols 153..167
    int r = tid / 15, c = 153 + tid % 15;
    s_mergedb[r * 168 + c] = 0;
  }

  const int i4 = tid >> 4, j4 = tid & 15;
  const int wid = tid >> 6, lane = tid & 63;
  const int lr = lane & 15, lk = lane >> 4;

  const float4* scalar4 = (const float4*)scalar_rep;
  const float4* vrep4 = (const float4*)vrep;

  for (int g = blockIdx.x; g < N_NODES / NB; g += gridDim.x) {
    const int n0 = g * NB;
    __syncthreads();   // previous iteration consumers done
    // stage scalar_rep -> bf16 merged[.,0:128]
    for (int idx = tid; idx < 512; idx += 256) {
      float4 v = scalar4[(size_t)n0 * 32 + idx];
      int r = idx >> 5, c4 = idx & 31;
      unsigned short* d = s_mergedb + r * 168 + c4 * 4;
      d[0] = f2bf(v.x); d[1] = f2bf(v.y); d[2] = f2bf(v.z); d[3] = f2bf(v.w);
    }
    // stage vector_rep f32
    for (int idx = tid; idx < 192; idx += 256)
      ((float4*)s_vrep)[idx] = vrep4[(size_t)n0 * 12 + idx];
    __syncthreads();
    // vh + vnorm
    {
      float a0 = 0.f, a1 = 0.f, a2 = 0.f;
#pragma unroll
      for (int v = 0; v < 16; ++v) {
        float w = s_WdT[v * 16 + j4];
        a0 += s_vrep[i4][v * 3 + 0] * w;
        a1 += s_vrep[i4][v * 3 + 1] * w;
        a2 += s_vrep[i4][v * 3 + 2] * w;
      }
      s_vh[i4][j4]      = a0;
      s_vh[i4][16 + j4] = a1;
      s_vh[i4][32 + j4] = a2;
      s_mergedb[i4 * 168 + 128 + j4] = f2bf(sqrtf(a0 * a0 + a1 * a1 + a2 * a2 + EPSV));
    }
    // vdf
    if (j4 < 9) {
      int t = j4 / 3, f = j4 - t * 3;
      float a = 0.f;
#pragma unroll
      for (int v = 0; v < 16; ++v)
        a += s_vrep[i4][v * 3 + t] * s_Wf[f * 16 + v];
      s_vdf[i4][j4] = a;
    }
    __syncthreads();
    // scalar_hidden -> merged[.,144:153]
    if (j4 < 9) {
      int f = j4 / 3, s = j4 - f * 3;
      const float* a = acc + (size_t)(n0 + i4) * 10;
      float c = fmaxf(a[9], 1.0f);
      float sum = a[s * 3 + 0] * s_vdf[i4][0 + f] +
                  a[s * 3 + 1] * s_vdf[i4][3 + f] +
                  a[s * 3 + 2] * s_vdf[i4][6 + f];
      s_mergedb[i4 * 168 + 144 + j4] = f2bf(sum / c);
    }
    __syncthreads();
    // big MFMA: merged[16x160] @ WsT[160x128]; wave wid owns N-tiles 2w,2w+1
    {
      const int nt0 = wid * 2;
      short8 afrag[5];
#pragma unroll
      for (int kk = 0; kk < 5; ++kk)
        afrag[kk] = *(const short8*)(s_mergedb + lr * 168 + kk * 32 + lk * 8);
      float b0v = s_bs[nt0 * 16 + lr], b1v = s_bs[nt0 * 16 + 16 + lr];
      f32x4 acc0 = {b0v, b0v, b0v, b0v};
      f32x4 acc1 = {b1v, b1v, b1v, b1v};
#pragma unroll
      for (int kk = 0; kk < 5; ++kk) {
        short8 bf0 = *(const short8*)(wsWs + (((nt0 * 5 + kk) << 6) + lane) * 8);
        short8 bf1 = *(const short8*)(wsWs + ((((nt0 + 1) * 5 + kk) << 6) + lane) * 8);
        acc0 = __builtin_amdgcn_mfma_f32_16x16x32_bf16(afrag[kk], bf0, acc0, 0, 0, 0);
        acc1 = __builtin_amdgcn_mfma_f32_16x16x32_bf16(afrag[kk], bf1, acc1, 0, 0, 0);
      }
#pragma unroll
      for (int j = 0; j < 4; ++j) {
        int node = lk * 4 + j;
        float x0 = acc0[j];
        float sf0 = x0 / (1.0f + __expf(-x0));
        out_s[(size_t)(n0 + node) * 128 + nt0 * 16 + lr] = sf0;
        s_sfb[node * 136 + nt0 * 16 + lr] = f2bf(sf0);
        float x1 = acc1[j];
        float sf1 = x1 / (1.0f + __expf(-x1));
        out_s[(size_t)(n0 + node) * 128 + nt0 * 16 + 16 + lr] = sf1;
        s_sfb[node * 136 + nt0 * 16 + 16 + lr] = f2bf(sf1);
      }
    }
    __syncthreads();
    // gate MFMA on wave 0: sf[16x128] @ WgT[128x16]
    if (wid == 0) {
      float gb = s_bg[lr];
      f32x4 gacc = {gb, gb, gb, gb};
#pragma unroll
      for (int kk = 0; kk < 4; ++kk) {
        short8 ga = *(const short8*)(s_sfb + lr * 136 + kk * 32 + lk * 8);
        short8 gw = *(const short8*)(wsWg + (((kk << 6) + lane) * 8));
        gacc = __builtin_amdgcn_mfma_f32_16x16x32_bf16(ga, gw, gacc, 0, 0, 0);
      }
#pragma unroll
      for (int j = 0; j < 4; ++j) {
        int node = lk * 4 + j;
        s_gate[node][lr] = 1.0f / (1.0f + __expf(-gacc[j]));
      }
    }
    __syncthreads();
    // v_up + gated output
    {
      float b0 = 0.f, b1 = 0.f, b2 = 0.f;
#pragma unroll
      for (int h = 0; h < 16; ++h) {
        float w = s_WuT[h * 16 + j4];
        b0 += s_vh[i4][h]      * w;
        b1 += s_vh[i4][16 + h] * w;
        b2 += s_vh[i4][32 + h] * w;
      }
      float gt = s_gate[i4][j4];
      size_t basep = (size_t)(n0 + i4) * 48 + (size_t)j4 * 3;
      out_v[basep + 0] = b0 * gt;
      out_v[basep + 1] = b1 * gt;
      out_v[basep + 2] = b2 * gt;
    }
  }
}

extern "C" void kernel_launch(void* const* d_in, const int* in_sizes, int n_in,
                              void* d_out, int out_size, void* d_ws, size_t ws_size,
                              hipStream_t stream) {
  const float* scalar_rep = (const float*)d_in[0];
  const float* vector_rep = (const float*)d_in[1];
  const float* frames     = (const float*)d_in[2];
  const float* W_down     = (const float*)d_in[3];
  const float* W_frames   = (const float*)d_in[4];
  const float* W_scalar   = (const float*)d_in[5];
  const float* b_scalar   = (const float*)d_in[6];
  const float* W_up       = (const float*)d_in[7];
  const float* W_gate     = (const float*)d_in[8];
  const float* b_gate     = (const float*)d_in[9];
  const int*   edge_index = (const int*)d_in[10];   // [2][E], row = first E

  float* out = (float*)d_out;

  // workspace layout (all regions multiples of 16 ints -> 16B aligned)
  int* ws = (int*)d_ws;
  int*   hist   = ws;                                  // 512*1563 = 800256
  int*   total  = hist + 800256;                       // 1600
  int*   base   = total + 1600;                        // 1600
  int*   sorted = base + 1600;                         // 3200000
  float* acc    = (float*)(sorted + 3200000);          // 1000000 floats
  unsigned short* wsWs = (unsigned short*)(acc + 1000000);  // 20480 bf16
  unsigned short* wsWg = wsWs + 20480;                      // 2048 bf16

  prep_kernel   <<<80,     256, 0, stream>>>(W_scalar, W_gate, wsWs, wsWg);
  hist_kernel   <<<NCHUNK, 256, 0, stream>>>(edge_index, hist);
  scanc_kernel  <<<NBUCK,  256, 0, stream>>>(hist, total);
  scanb_kernel  <<<1,      256, 0, stream>>>(total, base);
  scatter_kernel<<<NCHUNK, 256, 0, stream>>>(edge_index, hist, base, sorted);
  reduce_kernel <<<NBUCK,  256, 0, stream>>>(sorted, base, frames, acc);

  node_kernel<<<768, 256, 0, stream>>>(
      scalar_rep, vector_rep, W_down, W_frames, b_scalar,
      W_up, b_gate, wsWs, wsWg, acc,
      out, out + (size_t)N_NODES * 128);
}